// Round 12
// baseline (325.850 us; speedup 1.0000x reference)
//
#include <hip/hip_runtime.h>
#include <hip/hip_cooperative_groups.h>
#include <hip/hip_bf16.h>

namespace cg = cooperative_groups;

#define NN   12288
#define EE   393216
#define WELL 128                // ELL slots per row (pow2; max degree ~64)
#define NELL (NN*WELL)
#define BG   16
#define FIN  15
#define FH1  32
#define FH2  64
#define NCL  11
#define BNEPS 1e-5f
#define NBANK 32

typedef unsigned long long u64;
static inline int cdiv(long a, long b){ return (int)((a + b - 1) / b); }

__device__ __forceinline__ int getIdx(const void* p, long i, int is64){
  return is64 ? (int)((const long long*)p)[i] : ((const int*)p)[i];
}

__device__ __forceinline__ float degOf(u64 dc){
  return 1.0f + (float)(unsigned)(dc & 0xffffffffull) * (1.0f/1048576.0f);
}

// ---- pre: zero deg_cnt + colstat banks; detect int width (NO ELL fill) ----
__global__ void k_pre(u64* deg_cnt, float* csp1, float* csp2, float* csp3,
                      const void* ei, const void* batch, int* flags){
  int g = blockIdx.x*256 + threadIdx.x;
  if (g < NN) deg_cnt[g] = 0ull;
  if (g < NBANK*128){ csp1[g] = 0.f; csp2[g] = 0.f; csp3[g] = 0.f; }
  if (blockIdx.x == 0 && threadIdx.x < 64){
    const int* a = (const int*)ei;
    unsigned long long m0 = __ballot(a[2*threadIdx.x + 1] == 0);
    const int* b = (const int*)batch;
    int j = 96*threadIdx.x;
    unsigned long long m1 = __ballot(b[2*j + 1] == 0);
    if (threadIdx.x == 0){
      flags[0] = (m0 == ~0ull) ? 1 : 0;
      flags[1] = (m1 == ~0ull) ? 1 : 0;
    }
  }
}

// ---- edge pass: ONE u64 atomic per edge; returned count = ELL slot ----
__global__ void k_edge(const float* ea, const float* we, const float* bedg,
                       const void* ei, const int* flags, u64* deg_cnt, u64* csr_p){
  int e = blockIdx.x*256 + threadIdx.x;
  if (e >= EE) return;
  int is64 = flags[0];
  float2 eav = ((const float2*)ea)[e];
  float z = eav.x*we[0] + eav.y*we[1] + bedg[0];
  float w = 1.0f/(1.0f + expf(-z));
  int r = getIdx(ei, e, is64);
  int c = getIdx(ei, (long)EE + e, is64);
  u64 add = (1ull << 32) | (u64)__float2uint_rn(w * 1048576.0f);
  u64 old = atomicAdd(&deg_cnt[r], add);
  int slot = (int)(old >> 32);
  if (slot < WELL)
    csr_p[(r << 7) + slot] = (u64)(unsigned)c | ((u64)__float_as_uint(w) << 32);
}

// ---- fix pass: w *= rsqrt(deg[col]) for real slots only (pads untouched) ----
__global__ void k_fix(u64* csr_p, const u64* deg_cnt){
  int g = blockIdx.x*256 + threadIdx.x;
  if (g >= NELL) return;
  int row = g >> 7, s = g & (WELL-1);
  int n = (int)(deg_cnt[row] >> 32);
  n = n < WELL ? n : WELL;
  if (s >= n) return;
  u64 v = csr_p[g];
  int c = (int)(unsigned)(v & 0xffffffffull);
  float w = __uint_as_float((unsigned)(v >> 32)) * rsqrtf(degOf(deg_cnt[c]));
  ((unsigned*)csr_p)[2*g + 1] = __float_as_uint(w);
}

// ---- fused GCN layer, one tile per block, ELL chunks of 8 + prefetch.
// Tail slots masked in-register (pads are never zeroed in memory).
template<int F, int FP, int FO, int APPLY_BN>
__global__ void __launch_bounds__(256) k_layer(
    const float* __restrict__ Hin, const float* __restrict__ csin,
    const float* __restrict__ g, const float* __restrict__ be,
    const float* __restrict__ W, const float* __restrict__ bias,
    const u64* __restrict__ deg_cnt, const u64* __restrict__ csr_p,
    float* __restrict__ Pout, float* __restrict__ csout){
  const int R = 256/FP;
  __shared__ float At[R][FP];
  __shared__ float lcs[FO], lcq[FO];
  if (threadIdx.x < FO){ lcs[threadIdx.x] = 0.f; lcq[threadIdx.x] = 0.f; }
  int f = threadIdx.x % FP, lr = threadIdx.x / FP;
  float sc = 1.f, sh = 0.f;
  if (APPLY_BN && f < F){
    float s = 0.f, q = 0.f;
    #pragma unroll
    for (int b = 0; b < NBANK; b++){ s += csin[b*128 + f]; q += csin[b*128 + 64 + f]; }
    float mu  = s*(1.0f/NN);
    float var = q*(1.0f/NN) - mu*mu;
    float rinv = rsqrtf(var + BNEPS);
    sc = g[f]*rinv; sh = be[f] - mu*sc;
  }
  int row = blockIdx.x*R + lr;
  if (f < F){
    u64 dc = deg_cnt[row];
    float d = rsqrtf(degOf(dc));
    int n = (int)(dc >> 32);
    n = n < WELL ? n : WELL;
    float v0 = Hin[row*F + f];
    if (APPLY_BN) v0 = fmaxf(v0*sc + sh, 0.f);
    float acc = d * v0;                       // self loop
    int nch = (n + 7) >> 3;
    const uint4* pb = (const uint4*)(csr_p + ((long)row << 7));
    if (nch > 0){
      uint4 a0 = pb[0], a1 = pb[1], a2 = pb[2], a3 = pb[3];
      for (int ch = 0; ch < nch; ch++){
        uint4 b0, b1, b2, b3;
        bool more = (ch + 1 < nch);
        if (more){ b0 = pb[4*ch+4]; b1 = pb[4*ch+5]; b2 = pb[4*ch+6]; b3 = pb[4*ch+7]; }
        int base = ch*8;
        if (base + 8 > n){                    // mask garbage tail slots
          if (base+0 >= n){ a0.x = 0u; a0.y = 0u; }
          if (base+1 >= n){ a0.z = 0u; a0.w = 0u; }
          if (base+2 >= n){ a1.x = 0u; a1.y = 0u; }
          if (base+3 >= n){ a1.z = 0u; a1.w = 0u; }
          if (base+4 >= n){ a2.x = 0u; a2.y = 0u; }
          if (base+5 >= n){ a2.z = 0u; a2.w = 0u; }
          if (base+6 >= n){ a3.x = 0u; a3.y = 0u; }
          if (base+7 >= n){ a3.z = 0u; a3.w = 0u; }
        }
        float h0 = Hin[(int)a0.x*F + f];
        float h1 = Hin[(int)a0.z*F + f];
        float h2 = Hin[(int)a1.x*F + f];
        float h3 = Hin[(int)a1.z*F + f];
        float h4 = Hin[(int)a2.x*F + f];
        float h5 = Hin[(int)a2.z*F + f];
        float h6 = Hin[(int)a3.x*F + f];
        float h7 = Hin[(int)a3.z*F + f];
        if (APPLY_BN){
          h0 = fmaxf(h0*sc + sh, 0.f); h1 = fmaxf(h1*sc + sh, 0.f);
          h2 = fmaxf(h2*sc + sh, 0.f); h3 = fmaxf(h3*sc + sh, 0.f);
          h4 = fmaxf(h4*sc + sh, 0.f); h5 = fmaxf(h5*sc + sh, 0.f);
          h6 = fmaxf(h6*sc + sh, 0.f); h7 = fmaxf(h7*sc + sh, 0.f);
        }
        acc += __uint_as_float(a0.y)*h0 + __uint_as_float(a0.w)*h1
             + __uint_as_float(a1.y)*h2 + __uint_as_float(a1.w)*h3
             + __uint_as_float(a2.y)*h4 + __uint_as_float(a2.w)*h5
             + __uint_as_float(a3.y)*h6 + __uint_as_float(a3.w)*h7;
        if (more){ a0 = b0; a1 = b1; a2 = b2; a3 = b3; }
      }
    }
    At[lr][f] = d * acc;
  }
  __syncthreads();
  const int fo = threadIdx.x % FO;     // 256 % FO == 0
  float bb = bias[fo];
  for (int o = threadIdx.x; o < R*FO; o += 256){
    int l = o / FO;
    float s = bb;
    #pragma unroll
    for (int fi = 0; fi < F; fi++) s += At[l][fi] * W[fi*FO + fo];
    Pout[(blockIdx.x*R + l)*FO + fo] = s;
    atomicAdd(&lcs[fo], s);
    atomicAdd(&lcq[fo], s*s);
  }
  __syncthreads();
  if (threadIdx.x < FO){
    int bank = blockIdx.x & (NBANK-1);
    atomicAdd(&csout[bank*128 + threadIdx.x],      lcs[threadIdx.x]);
    atomicAdd(&csout[bank*128 + 64 + threadIdx.x], lcq[threadIdx.x]);
  }
}

// ---- fused tail: pool + fc1 + fc2 + fc3/log_softmax, 16 cooperative blocks ----
struct TailP {
  const float *P3, *cs3, *g3, *be3;
  const void *batch; const int *flags;
  const float *wf1,*bf1,*gf1,*bef1,*wf2,*bf2,*gf2,*bef2,*wf3,*bf3;
  float *embf, *s1g, *s2g, *out;
};

__global__ void __launch_bounds__(256) k_tail(TailP p){
  cg::grid_group grid = cg::this_grid();
  const int b = blockIdx.x, t = threadIdx.x;
  __shared__ float shpool[4][64];
  __shared__ float semb[BG*64];      // 4 KB
  __shared__ float s1l[BG*512];      // 32 KB
  __shared__ float s2l[256];
  __shared__ float sl[NCL];

  // ---- phase 1: pool graph b (BN3 on the fly) ----
  {
    int is64 = p.flags[1];
    int lo = 0, hi = NN;
    while (lo < hi){ int m = (lo+hi)>>1; if (getIdx(p.batch, m, is64) < b) lo = m+1; else hi = m; }
    int start = lo;
    lo = start; hi = NN;
    while (lo < hi){ int m = (lo+hi)>>1; if (getIdx(p.batch, m, is64) < b+1) lo = m+1; else hi = m; }
    int end = lo;
    int f = t & 63, grp = t >> 6;
    float s = 0.f, q = 0.f;
    #pragma unroll
    for (int bk = 0; bk < NBANK; bk++){ s += p.cs3[bk*128 + f]; q += p.cs3[bk*128 + 64 + f]; }
    float mu  = s*(1.0f/NN);
    float var = q*(1.0f/NN) - mu*mu;
    float rinv = rsqrtf(var + BNEPS);
    float sc = p.g3[f]*rinv, sh = p.be3[f] - mu*sc;
    float m = 0.0f;
    for (int i = start + grp; i < end; i += 4)
      m = fmaxf(m, p.P3[(long)i*FH2 + f]*sc + sh);
    shpool[grp][f] = m;
    __syncthreads();
    if (grp == 0){
      float v = fmaxf(fmaxf(shpool[0][f], shpool[1][f]), fmaxf(shpool[2][f], shpool[3][f]));
      p.embf[b*64 + f] = v;
      p.out[BG*NCL + b*64 + f] = v;
    }
  }
  grid.sync();

  // ---- phase 2: fc1+BN+relu — block b owns cols [b*32, b*32+32) ----
  for (int i = t; i < BG*64; i += 256) semb[i] = p.embf[i];
  __syncthreads();
  {
    int wv = t >> 6, l = t & 63;
    for (int i = 0; i < 8; i++){
      int c = b*32 + wv*8 + i;
      float wcol = p.wf1[l*512 + c];
      float z[BG];
      #pragma unroll
      for (int r = 0; r < BG; r++){
        float v = semb[r*64 + l] * wcol;
        #pragma unroll
        for (int off = 32; off > 0; off >>= 1) v += __shfl_down(v, off);
        z[r] = v;
      }
      if (l == 0){
        float bb = p.bf1[c];
        float s = 0.f, q = 0.f;
        #pragma unroll
        for (int r = 0; r < BG; r++){ float zr = z[r] + bb; s += zr; q += zr*zr; }
        float mean = s*(1.f/BG), var = q*(1.f/BG) - mean*mean;
        float inv = rsqrtf(var + BNEPS);
        float gg = p.gf1[c], b2 = p.bef1[c];
        #pragma unroll
        for (int r = 0; r < BG; r++)
          p.s1g[r*512 + c] = fmaxf(gg*(z[r] + bb - mean)*inv + b2, 0.f);
      }
    }
  }
  grid.sync();

  // ---- phase 3: fc2+BN+relu — block b owns cols [b*16, b*16+16) ----
  for (int i = t; i < BG*512; i += 256) s1l[i] = p.s1g[i];
  __syncthreads();
  {
    int wv = t >> 6, l = t & 63;
    for (int i = 0; i < 4; i++){
      int c = b*16 + wv*4 + i;
      float wr[8];
      #pragma unroll
      for (int j = 0; j < 8; j++) wr[j] = p.wf2[(l + 64*j)*256 + c];
      float z[BG];
      #pragma unroll
      for (int r = 0; r < BG; r++){
        float v = 0.f;
        #pragma unroll
        for (int j = 0; j < 8; j++) v += s1l[r*512 + l + 64*j] * wr[j];
        #pragma unroll
        for (int off = 32; off > 0; off >>= 1) v += __shfl_down(v, off);
        z[r] = v;
      }
      if (l == 0){
        float bb = p.bf2[c];
        float s = 0.f, q = 0.f;
        #pragma unroll
        for (int r = 0; r < BG; r++){ float zr = z[r] + bb; s += zr; q += zr*zr; }
        float mean = s*(1.f/BG), var = q*(1.f/BG) - mean*mean;
        float inv = rsqrtf(var + BNEPS);
        float gg = p.gf2[c], b2 = p.bef2[c];
        #pragma unroll
        for (int r = 0; r < BG; r++)
          p.s2g[r*256 + c] = fmaxf(gg*(z[r] + bb - mean)*inv + b2, 0.f);
      }
    }
  }
  grid.sync();

  // ---- phase 4: fc3 + log_softmax — block b owns graph b ----
  for (int i = t; i < 256; i += 256) s2l[i] = p.s2g[b*256 + i];
  __syncthreads();
  {
    int wv = t >> 6, l = t & 63;
    for (int cc = wv; cc < NCL; cc += 4){
      float v = 0.f;
      #pragma unroll
      for (int j = 0; j < 4; j++) v += s2l[l + 64*j] * p.wf3[(l + 64*j)*NCL + cc];
      #pragma unroll
      for (int off = 32; off > 0; off >>= 1) v += __shfl_down(v, off);
      if (l == 0) sl[cc] = v + p.bf3[cc];
    }
  }
  __syncthreads();
  if (t == 0){
    float m = -1e30f;
    for (int c = 0; c < NCL; c++) m = fmaxf(m, sl[c]);
    float s = 0.f;
    for (int c = 0; c < NCL; c++) s += expf(sl[c] - m);
    float lg = logf(s) + m;
    for (int c = 0; c < NCL; c++) p.out[b*NCL + c] = sl[c] - lg;
  }
}

extern "C" void kernel_launch(void* const* d_in, const int* in_sizes, int n_in,
                              void* d_out, int out_size, void* d_ws, size_t ws_size,
                              hipStream_t stream){
  const float* x    = (const float*)d_in[0];
  const float* ea   = (const float*)d_in[1];
  const float* we   = (const float*)d_in[2];
  const float* bedg = (const float*)d_in[3];
  const float* w1   = (const float*)d_in[4];  const float* b1  = (const float*)d_in[5];
  const float* g1   = (const float*)d_in[6];  const float* be1 = (const float*)d_in[7];
  const float* w2   = (const float*)d_in[8];  const float* b2  = (const float*)d_in[9];
  const float* g2   = (const float*)d_in[10]; const float* be2 = (const float*)d_in[11];
  const float* w3   = (const float*)d_in[12]; const float* b3  = (const float*)d_in[13];
  const float* g3   = (const float*)d_in[14]; const float* be3 = (const float*)d_in[15];
  const float* wf1  = (const float*)d_in[16]; const float* bf1 = (const float*)d_in[17];
  const float* gf1  = (const float*)d_in[18]; const float* bef1= (const float*)d_in[19];
  const float* wf2  = (const float*)d_in[20]; const float* bf2 = (const float*)d_in[21];
  const float* gf2  = (const float*)d_in[22]; const float* bef2= (const float*)d_in[23];
  const float* wf3  = (const float*)d_in[24]; const float* bf3 = (const float*)d_in[25];
  const void* ei    = d_in[26];
  const void* batch = d_in[27];
  float* out = (float*)d_out;

  u64* wq = (u64*)d_ws;
  u64* deg_cnt = wq; wq += NN;
  u64* csr_p   = wq; wq += NELL;
  float* ws = (float*)wq;
  float* P1    = ws; ws += NN*FH1;
  float* P2    = ws; ws += NN*FH2;
  float* P3    = ws; ws += NN*FH2;
  float* csp1  = ws; ws += NBANK*128;
  float* csp2  = ws; ws += NBANK*128;
  float* csp3  = ws; ws += NBANK*128;
  float* embf  = ws; ws += BG*64;
  float* s1g   = ws; ws += BG*512;
  float* s2g   = ws; ws += BG*256;
  int* flags   = (int*)ws;

  k_pre<<<48, 256, 0, stream>>>(deg_cnt, csp1, csp2, csp3, ei, batch, flags);
  k_edge<<<cdiv(EE,256), 256, 0, stream>>>(ea, we, bedg, ei, flags, deg_cnt, csr_p);
  k_fix<<<cdiv(NELL,256), 256, 0, stream>>>(csr_p, deg_cnt);

  // layer 1: x(15) -> P1(32)
  k_layer<FIN,16,FH1,0><<<NN/16, 256, 0, stream>>>(x, nullptr, nullptr, nullptr,
      w1, b1, deg_cnt, csr_p, P1, csp1);
  // layer 2: BN1(P1)(32) -> P2(64)
  k_layer<FH1,32,FH2,1><<<NN/8, 256, 0, stream>>>(P1, csp1, g1, be1,
      w2, b2, deg_cnt, csr_p, P2, csp2);
  // layer 3: BN2(P2)(64) -> P3(64)
  k_layer<FH2,64,FH2,1><<<NN/4, 256, 0, stream>>>(P2, csp2, g2, be2,
      w3, b3, deg_cnt, csr_p, P3, csp3);

  TailP tp;
  tp.P3 = P3; tp.cs3 = csp3; tp.g3 = g3; tp.be3 = be3;
  tp.batch = batch; tp.flags = flags;
  tp.wf1 = wf1; tp.bf1 = bf1; tp.gf1 = gf1; tp.bef1 = bef1;
  tp.wf2 = wf2; tp.bf2 = bf2; tp.gf2 = gf2; tp.bef2 = bef2;
  tp.wf3 = wf3; tp.bf3 = bf3;
  tp.embf = embf; tp.s1g = s1g; tp.s2g = s2g; tp.out = out;
  void* targs[] = { &tp };
  hipLaunchCooperativeKernel((const void*)k_tail, dim3(BG), dim3(256), targs, 0, stream);
}

// Round 13
// 265.002 us; speedup vs baseline: 1.2296x; 1.2296x over previous
//
#include <hip/hip_runtime.h>
#include <hip/hip_bf16.h>

#define NN   12288
#define EE   393216
#define WELL 128                // ELL slots per row (pow2; max degree ~64)
#define NELL (NN*WELL)
#define BG   16
#define FIN  15
#define FH1  32
#define FH2  64
#define NCL  11
#define BNEPS 1e-5f
#define NBANK 32

typedef unsigned long long u64;
static inline int cdiv(long a, long b){ return (int)((a + b - 1) / b); }

__device__ __forceinline__ int getIdx(const void* p, long i, int is64){
  return is64 ? (int)((const long long*)p)[i] : ((const int*)p)[i];
}

__device__ __forceinline__ float degOf(u64 dc){
  return 1.0f + (float)(unsigned)(dc & 0xffffffffull) * (1.0f/1048576.0f);
}

// ---- pre: zero deg_cnt + colstat banks; detect int width (NO ELL fill) ----
__global__ void k_pre(u64* deg_cnt, float* csp1, float* csp2, float* csp3,
                      const void* ei, const void* batch, int* flags){
  int g = blockIdx.x*256 + threadIdx.x;
  if (g < NN) deg_cnt[g] = 0ull;
  if (g < NBANK*128){ csp1[g] = 0.f; csp2[g] = 0.f; csp3[g] = 0.f; }
  if (blockIdx.x == 0 && threadIdx.x < 64){
    const int* a = (const int*)ei;
    unsigned long long m0 = __ballot(a[2*threadIdx.x + 1] == 0);
    const int* b = (const int*)batch;
    int j = 96*threadIdx.x;
    unsigned long long m1 = __ballot(b[2*j + 1] == 0);
    if (threadIdx.x == 0){
      flags[0] = (m0 == ~0ull) ? 1 : 0;
      flags[1] = (m1 == ~0ull) ? 1 : 0;
    }
  }
}

// ---- edge pass: ONE u64 atomic per edge; returned count = ELL slot ----
__global__ void k_edge(const float* ea, const float* we, const float* bedg,
                       const void* ei, const int* flags, u64* deg_cnt, u64* csr_p){
  int e = blockIdx.x*256 + threadIdx.x;
  if (e >= EE) return;
  int is64 = flags[0];
  float2 eav = ((const float2*)ea)[e];
  float z = eav.x*we[0] + eav.y*we[1] + bedg[0];
  float w = 1.0f/(1.0f + expf(-z));
  int r = getIdx(ei, e, is64);
  int c = getIdx(ei, (long)EE + e, is64);
  u64 add = (1ull << 32) | (u64)__float2uint_rn(w * 1048576.0f);
  u64 old = atomicAdd(&deg_cnt[r], add);
  int slot = (int)(old >> 32);
  if (slot < WELL)
    csr_p[(r << 7) + slot] = (u64)(unsigned)c | ((u64)__float_as_uint(w) << 32);
}

// ---- fix pass: w *= rsqrt(deg[col]) for real slots only (pads untouched) ----
__global__ void k_fix(u64* csr_p, const u64* deg_cnt){
  int g = blockIdx.x*256 + threadIdx.x;
  if (g >= NELL) return;
  int row = g >> 7, s = g & (WELL-1);
  int n = (int)(deg_cnt[row] >> 32);
  n = n < WELL ? n : WELL;
  if (s >= n) return;
  u64 v = csr_p[g];
  int c = (int)(unsigned)(v & 0xffffffffull);
  float w = __uint_as_float((unsigned)(v >> 32)) * rsqrtf(degOf(deg_cnt[c]));
  ((unsigned*)csr_p)[2*g + 1] = __float_as_uint(w);
}

// ---- fused GCN layer, one tile per block, ELL chunks of 8 + prefetch.
// Tail slots masked in-register (pads are never zeroed in memory).
template<int F, int FP, int FO, int APPLY_BN>
__global__ void __launch_bounds__(256) k_layer(
    const float* __restrict__ Hin, const float* __restrict__ csin,
    const float* __restrict__ g, const float* __restrict__ be,
    const float* __restrict__ W, const float* __restrict__ bias,
    const u64* __restrict__ deg_cnt, const u64* __restrict__ csr_p,
    float* __restrict__ Pout, float* __restrict__ csout){
  const int R = 256/FP;
  __shared__ float At[R][FP];
  __shared__ float lcs[FO], lcq[FO];
  if (threadIdx.x < FO){ lcs[threadIdx.x] = 0.f; lcq[threadIdx.x] = 0.f; }
  int f = threadIdx.x % FP, lr = threadIdx.x / FP;
  float sc = 1.f, sh = 0.f;
  if (APPLY_BN && f < F){
    float s = 0.f, q = 0.f;
    #pragma unroll
    for (int b = 0; b < NBANK; b++){ s += csin[b*128 + f]; q += csin[b*128 + 64 + f]; }
    float mu  = s*(1.0f/NN);
    float var = q*(1.0f/NN) - mu*mu;
    float rinv = rsqrtf(var + BNEPS);
    sc = g[f]*rinv; sh = be[f] - mu*sc;
  }
  int row = blockIdx.x*R + lr;
  if (f < F){
    u64 dc = deg_cnt[row];
    float d = rsqrtf(degOf(dc));
    int n = (int)(dc >> 32);
    n = n < WELL ? n : WELL;
    float v0 = Hin[row*F + f];
    if (APPLY_BN) v0 = fmaxf(v0*sc + sh, 0.f);
    float acc = d * v0;                       // self loop
    int nch = (n + 7) >> 3;
    const uint4* pb = (const uint4*)(csr_p + ((long)row << 7));
    if (nch > 0){
      uint4 a0 = pb[0], a1 = pb[1], a2 = pb[2], a3 = pb[3];
      for (int ch = 0; ch < nch; ch++){
        uint4 b0, b1, b2, b3;
        bool more = (ch + 1 < nch);
        if (more){ b0 = pb[4*ch+4]; b1 = pb[4*ch+5]; b2 = pb[4*ch+6]; b3 = pb[4*ch+7]; }
        int base = ch*8;
        if (base + 8 > n){                    // mask garbage tail slots
          if (base+0 >= n){ a0.x = 0u; a0.y = 0u; }
          if (base+1 >= n){ a0.z = 0u; a0.w = 0u; }
          if (base+2 >= n){ a1.x = 0u; a1.y = 0u; }
          if (base+3 >= n){ a1.z = 0u; a1.w = 0u; }
          if (base+4 >= n){ a2.x = 0u; a2.y = 0u; }
          if (base+5 >= n){ a2.z = 0u; a2.w = 0u; }
          if (base+6 >= n){ a3.x = 0u; a3.y = 0u; }
          if (base+7 >= n){ a3.z = 0u; a3.w = 0u; }
        }
        float h0 = Hin[(int)a0.x*F + f];
        float h1 = Hin[(int)a0.z*F + f];
        float h2 = Hin[(int)a1.x*F + f];
        float h3 = Hin[(int)a1.z*F + f];
        float h4 = Hin[(int)a2.x*F + f];
        float h5 = Hin[(int)a2.z*F + f];
        float h6 = Hin[(int)a3.x*F + f];
        float h7 = Hin[(int)a3.z*F + f];
        if (APPLY_BN){
          h0 = fmaxf(h0*sc + sh, 0.f); h1 = fmaxf(h1*sc + sh, 0.f);
          h2 = fmaxf(h2*sc + sh, 0.f); h3 = fmaxf(h3*sc + sh, 0.f);
          h4 = fmaxf(h4*sc + sh, 0.f); h5 = fmaxf(h5*sc + sh, 0.f);
          h6 = fmaxf(h6*sc + sh, 0.f); h7 = fmaxf(h7*sc + sh, 0.f);
        }
        acc += __uint_as_float(a0.y)*h0 + __uint_as_float(a0.w)*h1
             + __uint_as_float(a1.y)*h2 + __uint_as_float(a1.w)*h3
             + __uint_as_float(a2.y)*h4 + __uint_as_float(a2.w)*h5
             + __uint_as_float(a3.y)*h6 + __uint_as_float(a3.w)*h7;
        if (more){ a0 = b0; a1 = b1; a2 = b2; a3 = b3; }
      }
    }
    At[lr][f] = d * acc;
  }
  __syncthreads();
  const int fo = threadIdx.x % FO;     // 256 % FO == 0
  float bb = bias[fo];
  for (int o = threadIdx.x; o < R*FO; o += 256){
    int l = o / FO;
    float s = bb;
    #pragma unroll
    for (int fi = 0; fi < F; fi++) s += At[l][fi] * W[fi*FO + fo];
    Pout[(blockIdx.x*R + l)*FO + fo] = s;
    atomicAdd(&lcs[fo], s);
    atomicAdd(&lcq[fo], s*s);
  }
  __syncthreads();
  if (threadIdx.x < FO){
    int bank = blockIdx.x & (NBANK-1);
    atomicAdd(&csout[bank*128 + threadIdx.x],      lcs[threadIdx.x]);
    atomicAdd(&csout[bank*128 + 64 + threadIdx.x], lcq[threadIdx.x]);
  }
}

// ---- pool: BN3 on load, per-graph max, write embf + emb part of out ----
__global__ void k_pool(const float* P3, const float* cs3, const float* g3,
                       const float* be3, const void* batch, const int* flags,
                       float* embf, float* out){
  int is64 = flags[1];
  int b = blockIdx.x;
  int lo = 0, hi = NN;
  while (lo < hi){ int m = (lo+hi)>>1; if (getIdx(batch, m, is64) < b) lo = m+1; else hi = m; }
  int start = lo;
  lo = start; hi = NN;
  while (lo < hi){ int m = (lo+hi)>>1; if (getIdx(batch, m, is64) < b+1) lo = m+1; else hi = m; }
  int end = lo;
  int f = threadIdx.x & 63, grp = threadIdx.x >> 6;
  float s = 0.f, q = 0.f;
  #pragma unroll
  for (int bk = 0; bk < NBANK; bk++){ s += cs3[bk*128 + f]; q += cs3[bk*128 + 64 + f]; }
  float mu  = s*(1.0f/NN);
  float var = q*(1.0f/NN) - mu*mu;
  float rinv = rsqrtf(var + BNEPS);
  float sc = g3[f]*rinv, sh = be3[f] - mu*sc;
  float m = 0.0f;
  for (int i = start + grp; i < end; i += 4)
    m = fmaxf(m, P3[(long)i*FH2 + f]*sc + sh);
  __shared__ float shm[4][64];
  shm[grp][f] = m;
  __syncthreads();
  if (grp == 0){
    float v = fmaxf(fmaxf(shm[0][f], shm[1][f]), fmaxf(shm[2][f], shm[3][f]));
    embf[b*64 + f] = v;
    out[BG*NCL + b*64 + f] = v;
  }
}

// ---- head fc1 + BN + relu: wave per column ----
__global__ void __launch_bounds__(256) k_fcA(const float* embf, const float* wf1,
    const float* bf1, const float* gf1, const float* bef1, float* s1g){
  int c = blockIdx.x*4 + (threadIdx.x >> 6);
  int l = threadIdx.x & 63;
  float wcol = wf1[l*512 + c];
  float z[BG];
  #pragma unroll
  for (int r = 0; r < BG; r++){
    float v = embf[r*64 + l] * wcol;
    #pragma unroll
    for (int off = 32; off > 0; off >>= 1) v += __shfl_down(v, off);
    z[r] = v;                 // valid on lane 0
  }
  if (l == 0){
    float bb = bf1[c];
    float s = 0.f, q = 0.f;
    #pragma unroll
    for (int r = 0; r < BG; r++){ float zr = z[r] + bb; s += zr; q += zr*zr; }
    float mean = s*(1.f/BG), var = q*(1.f/BG) - mean*mean;
    float inv = rsqrtf(var + BNEPS);
    float gg = gf1[c], b2 = bef1[c];
    #pragma unroll
    for (int r = 0; r < BG; r++)
      s1g[r*512 + c] = fmaxf(gg*(z[r] + bb - mean)*inv + b2, 0.f);
  }
}

// ---- head fc2 + BN + relu: wave per column ----
__global__ void __launch_bounds__(256) k_fcB(const float* s1g, const float* wf2,
    const float* bf2, const float* gf2, const float* bef2, float* s2g){
  int c = blockIdx.x*4 + (threadIdx.x >> 6);
  int l = threadIdx.x & 63;
  float wreg[8];
  #pragma unroll
  for (int j = 0; j < 8; j++) wreg[j] = wf2[(l + 64*j)*256 + c];
  float z[BG];
  #pragma unroll
  for (int r = 0; r < BG; r++){
    float v = 0.f;
    #pragma unroll
    for (int j = 0; j < 8; j++) v += s1g[r*512 + l + 64*j] * wreg[j];
    #pragma unroll
    for (int off = 32; off > 0; off >>= 1) v += __shfl_down(v, off);
    z[r] = v;
  }
  if (l == 0){
    float bb = bf2[c];
    float s = 0.f, q = 0.f;
    #pragma unroll
    for (int r = 0; r < BG; r++){ float zr = z[r] + bb; s += zr; q += zr*zr; }
    float mean = s*(1.f/BG), var = q*(1.f/BG) - mean*mean;
    float inv = rsqrtf(var + BNEPS);
    float gg = gf2[c], b2 = bef2[c];
    #pragma unroll
    for (int r = 0; r < BG; r++)
      s2g[r*256 + c] = fmaxf(gg*(z[r] + bb - mean)*inv + b2, 0.f);
  }
}

// ---- head fc3 + log_softmax ----
__global__ void k_fc3(const float* s2g, const float* wf3, const float* bf3, float* out){
  __shared__ float s2[BG*256];
  __shared__ float sl[BG*NCL];
  int t = threadIdx.x;
  for (int i = t; i < BG*256; i += 256) s2[i] = s2g[i];
  __syncthreads();
  if (t < BG*NCL){
    int r = t / NCL, c = t - r*NCL;
    float s = bf3[c];
    for (int k = 0; k < 256; k++) s += s2[r*256 + k]*wf3[k*NCL + c];
    sl[t] = s;
  }
  __syncthreads();
  if (t < BG){
    float m = -1e30f;
    for (int c = 0; c < NCL; c++) m = fmaxf(m, sl[t*NCL + c]);
    float s = 0.f;
    for (int c = 0; c < NCL; c++) s += expf(sl[t*NCL + c] - m);
    float lg = logf(s) + m;
    for (int c = 0; c < NCL; c++) out[t*NCL + c] = sl[t*NCL + c] - lg;
  }
}

extern "C" void kernel_launch(void* const* d_in, const int* in_sizes, int n_in,
                              void* d_out, int out_size, void* d_ws, size_t ws_size,
                              hipStream_t stream){
  const float* x    = (const float*)d_in[0];
  const float* ea   = (const float*)d_in[1];
  const float* we   = (const float*)d_in[2];
  const float* bedg = (const float*)d_in[3];
  const float* w1   = (const float*)d_in[4];  const float* b1  = (const float*)d_in[5];
  const float* g1   = (const float*)d_in[6];  const float* be1 = (const float*)d_in[7];
  const float* w2   = (const float*)d_in[8];  const float* b2  = (const float*)d_in[9];
  const float* g2   = (const float*)d_in[10]; const float* be2 = (const float*)d_in[11];
  const float* w3   = (const float*)d_in[12]; const float* b3  = (const float*)d_in[13];
  const float* g3   = (const float*)d_in[14]; const float* be3 = (const float*)d_in[15];
  const float* wf1  = (const float*)d_in[16]; const float* bf1 = (const float*)d_in[17];
  const float* gf1  = (const float*)d_in[18]; const float* bef1= (const float*)d_in[19];
  const float* wf2  = (const float*)d_in[20]; const float* bf2 = (const float*)d_in[21];
  const float* gf2  = (const float*)d_in[22]; const float* bef2= (const float*)d_in[23];
  const float* wf3  = (const float*)d_in[24]; const float* bf3 = (const float*)d_in[25];
  const void* ei    = d_in[26];
  const void* batch = d_in[27];
  float* out = (float*)d_out;

  u64* wq = (u64*)d_ws;
  u64* deg_cnt = wq; wq += NN;
  u64* csr_p   = wq; wq += NELL;
  float* ws = (float*)wq;
  float* P1    = ws; ws += NN*FH1;
  float* P2    = ws; ws += NN*FH2;
  float* P3    = ws; ws += NN*FH2;
  float* csp1  = ws; ws += NBANK*128;
  float* csp2  = ws; ws += NBANK*128;
  float* csp3  = ws; ws += NBANK*128;
  float* embf  = ws; ws += BG*64;
  float* s1g   = ws; ws += BG*512;
  float* s2g   = ws; ws += BG*256;
  int* flags   = (int*)ws;

  k_pre<<<48, 256, 0, stream>>>(deg_cnt, csp1, csp2, csp3, ei, batch, flags);
  k_edge<<<cdiv(EE,256), 256, 0, stream>>>(ea, we, bedg, ei, flags, deg_cnt, csr_p);
  k_fix<<<cdiv(NELL,256), 256, 0, stream>>>(csr_p, deg_cnt);

  // layer 1: x(15) -> P1(32)
  k_layer<FIN,16,FH1,0><<<NN/16, 256, 0, stream>>>(x, nullptr, nullptr, nullptr,
      w1, b1, deg_cnt, csr_p, P1, csp1);
  // layer 2: BN1(P1)(32) -> P2(64)
  k_layer<FH1,32,FH2,1><<<NN/8, 256, 0, stream>>>(P1, csp1, g1, be1,
      w2, b2, deg_cnt, csr_p, P2, csp2);
  // layer 3: BN2(P2)(64) -> P3(64)
  k_layer<FH2,64,FH2,1><<<NN/4, 256, 0, stream>>>(P2, csp2, g2, be2,
      w3, b3, deg_cnt, csr_p, P3, csp3);

  k_pool<<<BG, 256, 0, stream>>>(P3, csp3, g3, be3, batch, flags, embf, out);
  k_fcA<<<128, 256, 0, stream>>>(embf, wf1, bf1, gf1, bef1, s1g);
  k_fcB<<<64, 256, 0, stream>>>(s1g, wf2, bf2, gf2, bef2, s2g);
  k_fc3<<<1, 256, 0, stream>>>(s2g, wf3, bf3, out);
}

// Round 14
// 234.345 us; speedup vs baseline: 1.3905x; 1.1308x over previous
//
#include <hip/hip_runtime.h>
#include <hip/hip_bf16.h>

#define NN   12288
#define EE   393216
#define WELL 128                // ELL slots per row (pow2; max degree ~64)
#define NELL (NN*WELL)
#define BG   16
#define FIN  15
#define FH1  32
#define FH2  64
#define NCL  11
#define BNEPS 1e-5f
#define NBANK 32

typedef unsigned long long u64;
static inline int cdiv(long a, long b){ return (int)((a + b - 1) / b); }

__device__ __forceinline__ int getIdx(const void* p, long i, int is64){
  return is64 ? (int)((const long long*)p)[i] : ((const int*)p)[i];
}

__device__ __forceinline__ float degOf(u64 dc){
  return 1.0f + (float)(unsigned)(dc & 0xffffffffull) * (1.0f/1048576.0f);
}

// ---- pre: zero deg_cnt + colstat banks + embf; detect int width ----
__global__ void k_pre(u64* deg_cnt, float* csp1, float* csp2, float* csp3,
                      float* embf, const void* ei, const void* batch, int* flags){
  int g = blockIdx.x*256 + threadIdx.x;
  if (g < NN) deg_cnt[g] = 0ull;
  if (g < NBANK*128){ csp1[g] = 0.f; csp2[g] = 0.f; csp3[g] = 0.f; }
  if (g < BG*64) embf[g] = 0.f;          // pool accumulates via atomicMax, vals >= 0
  if (blockIdx.x == 0 && threadIdx.x < 64){
    const int* a = (const int*)ei;
    unsigned long long m0 = __ballot(a[2*threadIdx.x + 1] == 0);
    const int* b = (const int*)batch;
    int j = 96*threadIdx.x;
    unsigned long long m1 = __ballot(b[2*j + 1] == 0);
    if (threadIdx.x == 0){
      flags[0] = (m0 == ~0ull) ? 1 : 0;
      flags[1] = (m1 == ~0ull) ? 1 : 0;
    }
  }
}

// ---- edge pass: ONE u64 atomic per edge; returned count = ELL slot ----
__global__ void k_edge(const float* ea, const float* we, const float* bedg,
                       const void* ei, const int* flags, u64* deg_cnt, u64* csr_p){
  int e = blockIdx.x*256 + threadIdx.x;
  if (e >= EE) return;
  int is64 = flags[0];
  float2 eav = ((const float2*)ea)[e];
  float z = eav.x*we[0] + eav.y*we[1] + bedg[0];
  float w = 1.0f/(1.0f + expf(-z));
  int r = getIdx(ei, e, is64);
  int c = getIdx(ei, (long)EE + e, is64);
  u64 add = (1ull << 32) | (u64)__float2uint_rn(w * 1048576.0f);
  u64 old = atomicAdd(&deg_cnt[r], add);
  int slot = (int)(old >> 32);
  if (slot < WELL)
    csr_p[(r << 7) + slot] = (u64)(unsigned)c | ((u64)__float_as_uint(w) << 32);
}

// ---- fix pass: w *= rsqrt(deg[col]) for real slots only (pads untouched) ----
__global__ void k_fix(u64* csr_p, const u64* deg_cnt){
  int g = blockIdx.x*256 + threadIdx.x;
  if (g >= NELL) return;
  int row = g >> 7, s = g & (WELL-1);
  int n = (int)(deg_cnt[row] >> 32);
  n = n < WELL ? n : WELL;
  if (s >= n) return;
  u64 v = csr_p[g];
  int c = (int)(unsigned)(v & 0xffffffffull);
  float w = __uint_as_float((unsigned)(v >> 32)) * rsqrtf(degOf(deg_cnt[c]));
  ((unsigned*)csr_p)[2*g + 1] = __float_as_uint(w);
}

// ---- fused GCN layer, one tile per block, ELL chunks of 8 + prefetch.
// Tail slots masked in-register (pads are never zeroed in memory).
template<int F, int FP, int FO, int APPLY_BN>
__global__ void __launch_bounds__(256) k_layer(
    const float* __restrict__ Hin, const float* __restrict__ csin,
    const float* __restrict__ g, const float* __restrict__ be,
    const float* __restrict__ W, const float* __restrict__ bias,
    const u64* __restrict__ deg_cnt, const u64* __restrict__ csr_p,
    float* __restrict__ Pout, float* __restrict__ csout){
  const int R = 256/FP;
  __shared__ float At[R][FP];
  __shared__ float lcs[FO], lcq[FO];
  if (threadIdx.x < FO){ lcs[threadIdx.x] = 0.f; lcq[threadIdx.x] = 0.f; }
  int f = threadIdx.x % FP, lr = threadIdx.x / FP;
  float sc = 1.f, sh = 0.f;
  if (APPLY_BN && f < F){
    float s = 0.f, q = 0.f;
    #pragma unroll
    for (int b = 0; b < NBANK; b++){ s += csin[b*128 + f]; q += csin[b*128 + 64 + f]; }
    float mu  = s*(1.0f/NN);
    float var = q*(1.0f/NN) - mu*mu;
    float rinv = rsqrtf(var + BNEPS);
    sc = g[f]*rinv; sh = be[f] - mu*sc;
  }
  int row = blockIdx.x*R + lr;
  if (f < F){
    u64 dc = deg_cnt[row];
    float d = rsqrtf(degOf(dc));
    int n = (int)(dc >> 32);
    n = n < WELL ? n : WELL;
    float v0 = Hin[row*F + f];
    if (APPLY_BN) v0 = fmaxf(v0*sc + sh, 0.f);
    float acc = d * v0;                       // self loop
    int nch = (n + 7) >> 3;
    const uint4* pb = (const uint4*)(csr_p + ((long)row << 7));
    if (nch > 0){
      uint4 a0 = pb[0], a1 = pb[1], a2 = pb[2], a3 = pb[3];
      for (int ch = 0; ch < nch; ch++){
        uint4 b0, b1, b2, b3;
        bool more = (ch + 1 < nch);
        if (more){ b0 = pb[4*ch+4]; b1 = pb[4*ch+5]; b2 = pb[4*ch+6]; b3 = pb[4*ch+7]; }
        int base = ch*8;
        if (base + 8 > n){                    // mask garbage tail slots
          if (base+0 >= n){ a0.x = 0u; a0.y = 0u; }
          if (base+1 >= n){ a0.z = 0u; a0.w = 0u; }
          if (base+2 >= n){ a1.x = 0u; a1.y = 0u; }
          if (base+3 >= n){ a1.z = 0u; a1.w = 0u; }
          if (base+4 >= n){ a2.x = 0u; a2.y = 0u; }
          if (base+5 >= n){ a2.z = 0u; a2.w = 0u; }
          if (base+6 >= n){ a3.x = 0u; a3.y = 0u; }
          if (base+7 >= n){ a3.z = 0u; a3.w = 0u; }
        }
        float h0 = Hin[(int)a0.x*F + f];
        float h1 = Hin[(int)a0.z*F + f];
        float h2 = Hin[(int)a1.x*F + f];
        float h3 = Hin[(int)a1.z*F + f];
        float h4 = Hin[(int)a2.x*F + f];
        float h5 = Hin[(int)a2.z*F + f];
        float h6 = Hin[(int)a3.x*F + f];
        float h7 = Hin[(int)a3.z*F + f];
        if (APPLY_BN){
          h0 = fmaxf(h0*sc + sh, 0.f); h1 = fmaxf(h1*sc + sh, 0.f);
          h2 = fmaxf(h2*sc + sh, 0.f); h3 = fmaxf(h3*sc + sh, 0.f);
          h4 = fmaxf(h4*sc + sh, 0.f); h5 = fmaxf(h5*sc + sh, 0.f);
          h6 = fmaxf(h6*sc + sh, 0.f); h7 = fmaxf(h7*sc + sh, 0.f);
        }
        acc += __uint_as_float(a0.y)*h0 + __uint_as_float(a0.w)*h1
             + __uint_as_float(a1.y)*h2 + __uint_as_float(a1.w)*h3
             + __uint_as_float(a2.y)*h4 + __uint_as_float(a2.w)*h5
             + __uint_as_float(a3.y)*h6 + __uint_as_float(a3.w)*h7;
        if (more){ a0 = b0; a1 = b1; a2 = b2; a3 = b3; }
      }
    }
    At[lr][f] = d * acc;
  }
  __syncthreads();
  const int fo = threadIdx.x % FO;     // 256 % FO == 0
  float bb = bias[fo];
  for (int o = threadIdx.x; o < R*FO; o += 256){
    int l = o / FO;
    float s = bb;
    #pragma unroll
    for (int fi = 0; fi < F; fi++) s += At[l][fi] * W[fi*FO + fo];
    Pout[(blockIdx.x*R + l)*FO + fo] = s;
    atomicAdd(&lcs[fo], s);
    atomicAdd(&lcq[fo], s*s);
  }
  __syncthreads();
  if (threadIdx.x < FO){
    int bank = blockIdx.x & (NBANK-1);
    atomicAdd(&csout[bank*128 + threadIdx.x],      lcs[threadIdx.x]);
    atomicAdd(&csout[bank*128 + 64 + threadIdx.x], lcq[threadIdx.x]);
  }
}

// ---- pool: 16 chunks per graph (256 blocks); BN3 on the fly; atomicMax merge.
// Pooled values are >= 0 (relu), so int-compare on float bits is monotone and
// the embf zero-init is the correct identity.
__global__ void k_pool(const float* P3, const float* cs3, const float* g3,
                       const float* be3, const void* batch, const int* flags,
                       float* embf){
  int is64 = flags[1];
  int b = blockIdx.x & 15, chunk = blockIdx.x >> 4;
  int lo = 0, hi = NN;
  while (lo < hi){ int m = (lo+hi)>>1; if (getIdx(batch, m, is64) < b) lo = m+1; else hi = m; }
  int start = lo;
  lo = start; hi = NN;
  while (lo < hi){ int m = (lo+hi)>>1; if (getIdx(batch, m, is64) < b+1) lo = m+1; else hi = m; }
  int end = lo;
  int f = threadIdx.x & 63, grp = threadIdx.x >> 6;
  float s = 0.f, q = 0.f;
  #pragma unroll
  for (int bk = 0; bk < NBANK; bk++){ s += cs3[bk*128 + f]; q += cs3[bk*128 + 64 + f]; }
  float mu  = s*(1.0f/NN);
  float var = q*(1.0f/NN) - mu*mu;
  float rinv = rsqrtf(var + BNEPS);
  float sc = g3[f]*rinv, sh = be3[f] - mu*sc;
  float m = 0.0f;
  for (int i = start + chunk*4 + grp; i < end; i += 64)
    m = fmaxf(m, P3[(long)i*FH2 + f]*sc + sh);
  __shared__ float shm[4][64];
  shm[grp][f] = m;
  __syncthreads();
  if (grp == 0){
    float v = fmaxf(fmaxf(shm[0][f], shm[1][f]), fmaxf(shm[2][f], shm[3][f]));
    atomicMax((int*)&embf[b*64 + f], __float_as_int(v));
  }
}

// ---- head fc1 + BN + relu: wave per column; block 0 also copies emb -> out ----
__global__ void __launch_bounds__(256) k_fcA(const float* embf, const float* wf1,
    const float* bf1, const float* gf1, const float* bef1, float* s1g, float* out){
  if (blockIdx.x == 0){
    #pragma unroll
    for (int i = 0; i < 4; i++)
      out[BG*NCL + i*256 + threadIdx.x] = embf[i*256 + threadIdx.x];
  }
  int c = blockIdx.x*4 + (threadIdx.x >> 6);
  int l = threadIdx.x & 63;
  float wcol = wf1[l*512 + c];
  float z[BG];
  #pragma unroll
  for (int r = 0; r < BG; r++){
    float v = embf[r*64 + l] * wcol;
    #pragma unroll
    for (int off = 32; off > 0; off >>= 1) v += __shfl_down(v, off);
    z[r] = v;                 // valid on lane 0
  }
  if (l == 0){
    float bb = bf1[c];
    float s = 0.f, q = 0.f;
    #pragma unroll
    for (int r = 0; r < BG; r++){ float zr = z[r] + bb; s += zr; q += zr*zr; }
    float mean = s*(1.f/BG), var = q*(1.f/BG) - mean*mean;
    float inv = rsqrtf(var + BNEPS);
    float gg = gf1[c], b2 = bef1[c];
    #pragma unroll
    for (int r = 0; r < BG; r++)
      s1g[r*512 + c] = fmaxf(gg*(z[r] + bb - mean)*inv + b2, 0.f);
  }
}

// ---- head fc2 + BN + relu: wave per column ----
__global__ void __launch_bounds__(256) k_fcB(const float* s1g, const float* wf2,
    const float* bf2, const float* gf2, const float* bef2, float* s2g){
  int c = blockIdx.x*4 + (threadIdx.x >> 6);
  int l = threadIdx.x & 63;
  float wreg[8];
  #pragma unroll
  for (int j = 0; j < 8; j++) wreg[j] = wf2[(l + 64*j)*256 + c];
  float z[BG];
  #pragma unroll
  for (int r = 0; r < BG; r++){
    float v = 0.f;
    #pragma unroll
    for (int j = 0; j < 8; j++) v += s1g[r*512 + l + 64*j] * wreg[j];
    #pragma unroll
    for (int off = 32; off > 0; off >>= 1) v += __shfl_down(v, off);
    z[r] = v;
  }
  if (l == 0){
    float bb = bf2[c];
    float s = 0.f, q = 0.f;
    #pragma unroll
    for (int r = 0; r < BG; r++){ float zr = z[r] + bb; s += zr; q += zr*zr; }
    float mean = s*(1.f/BG), var = q*(1.f/BG) - mean*mean;
    float inv = rsqrtf(var + BNEPS);
    float gg = gf2[c], b2 = bef2[c];
    #pragma unroll
    for (int r = 0; r < BG; r++)
      s2g[r*256 + c] = fmaxf(gg*(z[r] + bb - mean)*inv + b2, 0.f);
  }
}

// ---- head fc3 + log_softmax ----
__global__ void k_fc3(const float* s2g, const float* wf3, const float* bf3, float* out){
  __shared__ float s2[BG*256];
  __shared__ float sl[BG*NCL];
  int t = threadIdx.x;
  for (int i = t; i < BG*256; i += 256) s2[i] = s2g[i];
  __syncthreads();
  if (t < BG*NCL){
    int r = t / NCL, c = t - r*NCL;
    float s = bf3[c];
    for (int k = 0; k < 256; k++) s += s2[r*256 + k]*wf3[k*NCL + c];
    sl[t] = s;
  }
  __syncthreads();
  if (t < BG){
    float m = -1e30f;
    for (int c = 0; c < NCL; c++) m = fmaxf(m, sl[t*NCL + c]);
    float s = 0.f;
    for (int c = 0; c < NCL; c++) s += expf(sl[t*NCL + c] - m);
    float lg = logf(s) + m;
    for (int c = 0; c < NCL; c++) out[t*NCL + c] = sl[t*NCL + c] - lg;
  }
}

extern "C" void kernel_launch(void* const* d_in, const int* in_sizes, int n_in,
                              void* d_out, int out_size, void* d_ws, size_t ws_size,
                              hipStream_t stream){
  const float* x    = (const float*)d_in[0];
  const float* ea   = (const float*)d_in[1];
  const float* we   = (const float*)d_in[2];
  const float* bedg = (const float*)d_in[3];
  const float* w1   = (const float*)d_in[4];  const float* b1  = (const float*)d_in[5];
  const float* g1   = (const float*)d_in[6];  const float* be1 = (const float*)d_in[7];
  const float* w2   = (const float*)d_in[8];  const float* b2  = (const float*)d_in[9];
  const float* g2   = (const float*)d_in[10]; const float* be2 = (const float*)d_in[11];
  const float* w3   = (const float*)d_in[12]; const float* b3  = (const float*)d_in[13];
  const float* g3   = (const float*)d_in[14]; const float* be3 = (const float*)d_in[15];
  const float* wf1  = (const float*)d_in[16]; const float* bf1 = (const float*)d_in[17];
  const float* gf1  = (const float*)d_in[18]; const float* bef1= (const float*)d_in[19];
  const float* wf2  = (const float*)d_in[20]; const float* bf2 = (const float*)d_in[21];
  const float* gf2  = (const float*)d_in[22]; const float* bef2= (const float*)d_in[23];
  const float* wf3  = (const float*)d_in[24]; const float* bf3 = (const float*)d_in[25];
  const void* ei    = d_in[26];
  const void* batch = d_in[27];
  float* out = (float*)d_out;

  u64* wq = (u64*)d_ws;
  u64* deg_cnt = wq; wq += NN;
  u64* csr_p   = wq; wq += NELL;
  float* ws = (float*)wq;
  float* P1    = ws; ws += NN*FH1;
  float* P2    = ws; ws += NN*FH2;
  float* P3    = ws; ws += NN*FH2;
  float* csp1  = ws; ws += NBANK*128;
  float* csp2  = ws; ws += NBANK*128;
  float* csp3  = ws; ws += NBANK*128;
  float* embf  = ws; ws += BG*64;
  float* s1g   = ws; ws += BG*512;
  float* s2g   = ws; ws += BG*256;
  int* flags   = (int*)ws;

  k_pre<<<48, 256, 0, stream>>>(deg_cnt, csp1, csp2, csp3, embf, ei, batch, flags);
  k_edge<<<cdiv(EE,256), 256, 0, stream>>>(ea, we, bedg, ei, flags, deg_cnt, csr_p);
  k_fix<<<cdiv(NELL,256), 256, 0, stream>>>(csr_p, deg_cnt);

  // layer 1: x(15) -> P1(32)
  k_layer<FIN,16,FH1,0><<<NN/16, 256, 0, stream>>>(x, nullptr, nullptr, nullptr,
      w1, b1, deg_cnt, csr_p, P1, csp1);
  // layer 2: BN1(P1)(32) -> P2(64)
  k_layer<FH1,32,FH2,1><<<NN/8, 256, 0, stream>>>(P1, csp1, g1, be1,
      w2, b2, deg_cnt, csr_p, P2, csp2);
  // layer 3: BN2(P2)(64) -> P3(64)
  k_layer<FH2,64,FH2,1><<<NN/4, 256, 0, stream>>>(P2, csp2, g2, be2,
      w3, b3, deg_cnt, csr_p, P3, csp3);

  k_pool<<<256, 256, 0, stream>>>(P3, csp3, g3, be3, batch, flags, embf);
  k_fcA<<<128, 256, 0, stream>>>(embf, wf1, bf1, gf1, bef1, s1g, out);
  k_fcB<<<64, 256, 0, stream>>>(s1g, wf2, bf2, gf2, bef2, s2g);
  k_fc3<<<1, 256, 0, stream>>>(s2g, wf3, bf3, out);
}

// Round 15
// 230.031 us; speedup vs baseline: 1.4166x; 1.0188x over previous
//
#include <hip/hip_runtime.h>
#include <hip/hip_bf16.h>

#define NN   12288
#define EE   393216
#define WELL 128                // ELL slots per row (pow2; max degree ~64)
#define NELL (NN*WELL)
#define BG   16
#define FIN  15
#define FH1  32
#define FH2  64
#define NCL  11
#define BNEPS 1e-5f
#define NBANK 32

typedef unsigned long long u64;
static inline int cdiv(long a, long b){ return (int)((a + b - 1) / b); }

__device__ __forceinline__ int getIdx(const void* p, long i, int is64){
  return is64 ? (int)((const long long*)p)[i] : ((const int*)p)[i];
}

__device__ __forceinline__ float degOf(u64 dc){
  return 1.0f + (float)(unsigned)(dc & 0xffffffffull) * (1.0f/1048576.0f);
}

// ---- pre: zero deg_cnt + colstat banks + embf; detect int width ----
__global__ void k_pre(u64* deg_cnt, float* csp1, float* csp2, float* csp3,
                      float* embf, const void* ei, const void* batch, int* flags){
  int g = blockIdx.x*256 + threadIdx.x;
  if (g < NN) deg_cnt[g] = 0ull;
  if (g < NBANK*128){ csp1[g] = 0.f; csp2[g] = 0.f; csp3[g] = 0.f; }
  if (g < BG*64) embf[g] = 0.f;          // pool accumulates via atomicMax, vals >= 0
  if (blockIdx.x == 0 && threadIdx.x < 64){
    const int* a = (const int*)ei;
    unsigned long long m0 = __ballot(a[2*threadIdx.x + 1] == 0);
    const int* b = (const int*)batch;
    int j = 96*threadIdx.x;
    unsigned long long m1 = __ballot(b[2*j + 1] == 0);
    if (threadIdx.x == 0){
      flags[0] = (m0 == ~0ull) ? 1 : 0;
      flags[1] = (m1 == ~0ull) ? 1 : 0;
    }
  }
}

// ---- edge pass: ONE u64 atomic per edge; returned count = ELL slot ----
__global__ void k_edge(const float* ea, const float* we, const float* bedg,
                       const void* ei, const int* flags, u64* deg_cnt, u64* csr_p){
  int e = blockIdx.x*256 + threadIdx.x;
  if (e >= EE) return;
  int is64 = flags[0];
  float2 eav = ((const float2*)ea)[e];
  float z = eav.x*we[0] + eav.y*we[1] + bedg[0];
  float w = 1.0f/(1.0f + expf(-z));
  int r = getIdx(ei, e, is64);
  int c = getIdx(ei, (long)EE + e, is64);
  u64 add = (1ull << 32) | (u64)__float2uint_rn(w * 1048576.0f);
  u64 old = atomicAdd(&deg_cnt[r], add);
  int slot = (int)(old >> 32);
  if (slot < WELL)
    csr_p[(r << 7) + slot] = (u64)(unsigned)c | ((u64)__float_as_uint(w) << 32);
}

// ---- fix pass: w *= rsqrt(deg[col]) for real slots only (pads untouched) ----
__global__ void k_fix(u64* csr_p, const u64* deg_cnt){
  int g = blockIdx.x*256 + threadIdx.x;
  if (g >= NELL) return;
  int row = g >> 7, s = g & (WELL-1);
  int n = (int)(deg_cnt[row] >> 32);
  n = n < WELL ? n : WELL;
  if (s >= n) return;
  u64 v = csr_p[g];
  int c = (int)(unsigned)(v & 0xffffffffull);
  float w = __uint_as_float((unsigned)(v >> 32)) * rsqrtf(degOf(deg_cnt[c]));
  ((unsigned*)csr_p)[2*g + 1] = __float_as_uint(w);
}

// ---- BN coefficient prep: banks + gamma/beta -> (sc, sh), once per layer ----
template<int F>
__global__ void k_stat(const float* csp, const float* g, const float* be, float* scsh){
  int f = threadIdx.x;
  if (f >= F) return;
  float s = 0.f, q = 0.f;
  #pragma unroll
  for (int b = 0; b < NBANK; b++){ s += csp[b*128 + f]; q += csp[b*128 + 64 + f]; }
  float mu  = s*(1.0f/NN);
  float var = q*(1.0f/NN) - mu*mu;
  float rinv = rsqrtf(var + BNEPS);
  float sc = g[f]*rinv;
  scsh[f]      = sc;
  scsh[64 + f] = be[f] - mu*sc;
}

// ---- fused GCN layer, one tile per block, ELL chunks of 8 + prefetch.
// Tail slots masked in-register; BN coefficients preloaded from scsh.
template<int F, int FP, int FO, int APPLY_BN>
__global__ void __launch_bounds__(256) k_layer(
    const float* __restrict__ Hin, const float* __restrict__ scsh,
    const float* __restrict__ W, const float* __restrict__ bias,
    const u64* __restrict__ deg_cnt, const u64* __restrict__ csr_p,
    float* __restrict__ Pout, float* __restrict__ csout){
  const int R = 256/FP;
  __shared__ float At[R][FP];
  __shared__ float lcs[FO], lcq[FO];
  if (threadIdx.x < FO){ lcs[threadIdx.x] = 0.f; lcq[threadIdx.x] = 0.f; }
  int f = threadIdx.x % FP, lr = threadIdx.x / FP;
  float sc = 1.f, sh = 0.f;
  if (APPLY_BN && f < F){ sc = scsh[f]; sh = scsh[64 + f]; }
  int row = blockIdx.x*R + lr;
  if (f < F){
    u64 dc = deg_cnt[row];
    float d = rsqrtf(degOf(dc));
    int n = (int)(dc >> 32);
    n = n < WELL ? n : WELL;
    float v0 = Hin[row*F + f];
    if (APPLY_BN) v0 = fmaxf(v0*sc + sh, 0.f);
    float acc = d * v0;                       // self loop
    int nch = (n + 7) >> 3;
    const uint4* pb = (const uint4*)(csr_p + ((long)row << 7));
    if (nch > 0){
      uint4 a0 = pb[0], a1 = pb[1], a2 = pb[2], a3 = pb[3];
      for (int ch = 0; ch < nch; ch++){
        uint4 b0, b1, b2, b3;
        bool more = (ch + 1 < nch);
        if (more){ b0 = pb[4*ch+4]; b1 = pb[4*ch+5]; b2 = pb[4*ch+6]; b3 = pb[4*ch+7]; }
        int base = ch*8;
        if (base + 8 > n){                    // mask garbage tail slots
          if (base+0 >= n){ a0.x = 0u; a0.y = 0u; }
          if (base+1 >= n){ a0.z = 0u; a0.w = 0u; }
          if (base+2 >= n){ a1.x = 0u; a1.y = 0u; }
          if (base+3 >= n){ a1.z = 0u; a1.w = 0u; }
          if (base+4 >= n){ a2.x = 0u; a2.y = 0u; }
          if (base+5 >= n){ a2.z = 0u; a2.w = 0u; }
          if (base+6 >= n){ a3.x = 0u; a3.y = 0u; }
          if (base+7 >= n){ a3.z = 0u; a3.w = 0u; }
        }
        float h0 = Hin[(int)a0.x*F + f];
        float h1 = Hin[(int)a0.z*F + f];
        float h2 = Hin[(int)a1.x*F + f];
        float h3 = Hin[(int)a1.z*F + f];
        float h4 = Hin[(int)a2.x*F + f];
        float h5 = Hin[(int)a2.z*F + f];
        float h6 = Hin[(int)a3.x*F + f];
        float h7 = Hin[(int)a3.z*F + f];
        if (APPLY_BN){
          h0 = fmaxf(h0*sc + sh, 0.f); h1 = fmaxf(h1*sc + sh, 0.f);
          h2 = fmaxf(h2*sc + sh, 0.f); h3 = fmaxf(h3*sc + sh, 0.f);
          h4 = fmaxf(h4*sc + sh, 0.f); h5 = fmaxf(h5*sc + sh, 0.f);
          h6 = fmaxf(h6*sc + sh, 0.f); h7 = fmaxf(h7*sc + sh, 0.f);
        }
        acc += __uint_as_float(a0.y)*h0 + __uint_as_float(a0.w)*h1
             + __uint_as_float(a1.y)*h2 + __uint_as_float(a1.w)*h3
             + __uint_as_float(a2.y)*h4 + __uint_as_float(a2.w)*h5
             + __uint_as_float(a3.y)*h6 + __uint_as_float(a3.w)*h7;
        if (more){ a0 = b0; a1 = b1; a2 = b2; a3 = b3; }
      }
    }
    At[lr][f] = d * acc;
  }
  __syncthreads();
  const int fo = threadIdx.x % FO;     // 256 % FO == 0
  float bb = bias[fo];
  for (int o = threadIdx.x; o < R*FO; o += 256){
    int l = o / FO;
    float s = bb;
    #pragma unroll
    for (int fi = 0; fi < F; fi++) s += At[l][fi] * W[fi*FO + fo];
    Pout[(blockIdx.x*R + l)*FO + fo] = s;
    atomicAdd(&lcs[fo], s);
    atomicAdd(&lcq[fo], s*s);
  }
  __syncthreads();
  if (threadIdx.x < FO){
    int bank = blockIdx.x & (NBANK-1);
    atomicAdd(&csout[bank*128 + threadIdx.x],      lcs[threadIdx.x]);
    atomicAdd(&csout[bank*128 + 64 + threadIdx.x], lcq[threadIdx.x]);
  }
}

// ---- pool: 16 chunks per graph (256 blocks); BN3 via scsh; atomicMax merge.
// Pooled values >= 0 (relu): int-compare on float bits is monotone; zero-init ok.
__global__ void k_pool(const float* P3, const float* scsh, const void* batch,
                       const int* flags, float* embf){
  int is64 = flags[1];
  int b = blockIdx.x & 15, chunk = blockIdx.x >> 4;
  int lo = 0, hi = NN;
  while (lo < hi){ int m = (lo+hi)>>1; if (getIdx(batch, m, is64) < b) lo = m+1; else hi = m; }
  int start = lo;
  lo = start; hi = NN;
  while (lo < hi){ int m = (lo+hi)>>1; if (getIdx(batch, m, is64) < b+1) lo = m+1; else hi = m; }
  int end = lo;
  int f = threadIdx.x & 63, grp = threadIdx.x >> 6;
  float sc = scsh[f], sh = scsh[64 + f];
  float m = 0.0f;
  for (int i = start + chunk*4 + grp; i < end; i += 64)
    m = fmaxf(m, P3[(long)i*FH2 + f]*sc + sh);
  __shared__ float shm[4][64];
  shm[grp][f] = m;
  __syncthreads();
  if (grp == 0){
    float v = fmaxf(fmaxf(shm[0][f], shm[1][f]), fmaxf(shm[2][f], shm[3][f]));
    atomicMax((int*)&embf[b*64 + f], __float_as_int(v));
  }
}

// ---- head fc1 + BN + relu: wave per column; block 0 also copies emb -> out ----
__global__ void __launch_bounds__(256) k_fcA(const float* embf, const float* wf1,
    const float* bf1, const float* gf1, const float* bef1, float* s1g, float* out){
  if (blockIdx.x == 0){
    #pragma unroll
    for (int i = 0; i < 4; i++)
      out[BG*NCL + i*256 + threadIdx.x] = embf[i*256 + threadIdx.x];
  }
  int c = blockIdx.x*4 + (threadIdx.x >> 6);
  int l = threadIdx.x & 63;
  float wcol = wf1[l*512 + c];
  float z[BG];
  #pragma unroll
  for (int r = 0; r < BG; r++){
    float v = embf[r*64 + l] * wcol;
    #pragma unroll
    for (int off = 32; off > 0; off >>= 1) v += __shfl_down(v, off);
    z[r] = v;                 // valid on lane 0
  }
  if (l == 0){
    float bb = bf1[c];
    float s = 0.f, q = 0.f;
    #pragma unroll
    for (int r = 0; r < BG; r++){ float zr = z[r] + bb; s += zr; q += zr*zr; }
    float mean = s*(1.f/BG), var = q*(1.f/BG) - mean*mean;
    float inv = rsqrtf(var + BNEPS);
    float gg = gf1[c], b2 = bef1[c];
    #pragma unroll
    for (int r = 0; r < BG; r++)
      s1g[r*512 + c] = fmaxf(gg*(z[r] + bb - mean)*inv + b2, 0.f);
  }
}

// ---- head fc2 + BN + relu: wave per column ----
__global__ void __launch_bounds__(256) k_fcB(const float* s1g, const float* wf2,
    const float* bf2, const float* gf2, const float* bef2, float* s2g){
  int c = blockIdx.x*4 + (threadIdx.x >> 6);
  int l = threadIdx.x & 63;
  float wreg[8];
  #pragma unroll
  for (int j = 0; j < 8; j++) wreg[j] = wf2[(l + 64*j)*256 + c];
  float z[BG];
  #pragma unroll
  for (int r = 0; r < BG; r++){
    float v = 0.f;
    #pragma unroll
    for (int j = 0; j < 8; j++) v += s1g[r*512 + l + 64*j] * wreg[j];
    #pragma unroll
    for (int off = 32; off > 0; off >>= 1) v += __shfl_down(v, off);
    z[r] = v;
  }
  if (l == 0){
    float bb = bf2[c];
    float s = 0.f, q = 0.f;
    #pragma unroll
    for (int r = 0; r < BG; r++){ float zr = z[r] + bb; s += zr; q += zr*zr; }
    float mean = s*(1.f/BG), var = q*(1.f/BG) - mean*mean;
    float inv = rsqrtf(var + BNEPS);
    float gg = gf2[c], b2 = bef2[c];
    #pragma unroll
    for (int r = 0; r < BG; r++)
      s2g[r*256 + c] = fmaxf(gg*(z[r] + bb - mean)*inv + b2, 0.f);
  }
}

// ---- head fc3 + log_softmax ----
__global__ void k_fc3(const float* s2g, const float* wf3, const float* bf3, float* out){
  __shared__ float s2[BG*256];
  __shared__ float sl[BG*NCL];
  int t = threadIdx.x;
  for (int i = t; i < BG*256; i += 256) s2[i] = s2g[i];
  __syncthreads();
  if (t < BG*NCL){
    int r = t / NCL, c = t - r*NCL;
    float s = bf3[c];
    for (int k = 0; k < 256; k++) s += s2[r*256 + k]*wf3[k*NCL + c];
    sl[t] = s;
  }
  __syncthreads();
  if (t < BG){
    float m = -1e30f;
    for (int c = 0; c < NCL; c++) m = fmaxf(m, sl[t*NCL + c]);
    float s = 0.f;
    for (int c = 0; c < NCL; c++) s += expf(sl[t*NCL + c] - m);
    float lg = logf(s) + m;
    for (int c = 0; c < NCL; c++) out[t*NCL + c] = sl[t*NCL + c] - lg;
  }
}

extern "C" void kernel_launch(void* const* d_in, const int* in_sizes, int n_in,
                              void* d_out, int out_size, void* d_ws, size_t ws_size,
                              hipStream_t stream){
  const float* x    = (const float*)d_in[0];
  const float* ea   = (const float*)d_in[1];
  const float* we   = (const float*)d_in[2];
  const float* bedg = (const float*)d_in[3];
  const float* w1   = (const float*)d_in[4];  const float* b1  = (const float*)d_in[5];
  const float* g1   = (const float*)d_in[6];  const float* be1 = (const float*)d_in[7];
  const float* w2   = (const float*)d_in[8];  const float* b2  = (const float*)d_in[9];
  const float* g2   = (const float*)d_in[10]; const float* be2 = (const float*)d_in[11];
  const float* w3   = (const float*)d_in[12]; const float* b3  = (const float*)d_in[13];
  const float* g3   = (const float*)d_in[14]; const float* be3 = (const float*)d_in[15];
  const float* wf1  = (const float*)d_in[16]; const float* bf1 = (const float*)d_in[17];
  const float* gf1  = (const float*)d_in[18]; const float* bef1= (const float*)d_in[19];
  const float* wf2  = (const float*)d_in[20]; const float* bf2 = (const float*)d_in[21];
  const float* gf2  = (const float*)d_in[22]; const float* bef2= (const float*)d_in[23];
  const float* wf3  = (const float*)d_in[24]; const float* bf3 = (const float*)d_in[25];
  const void* ei    = d_in[26];
  const void* batch = d_in[27];
  float* out = (float*)d_out;

  u64* wq = (u64*)d_ws;
  u64* deg_cnt = wq; wq += NN;
  u64* csr_p   = wq; wq += NELL;
  float* ws = (float*)wq;
  float* P1    = ws; ws += NN*FH1;
  float* P2    = ws; ws += NN*FH2;
  float* P3    = ws; ws += NN*FH2;
  float* csp1  = ws; ws += NBANK*128;
  float* csp2  = ws; ws += NBANK*128;
  float* csp3  = ws; ws += NBANK*128;
  float* scs1  = ws; ws += 128;
  float* scs2  = ws; ws += 128;
  float* scs3  = ws; ws += 128;
  float* embf  = ws; ws += BG*64;
  float* s1g   = ws; ws += BG*512;
  float* s2g   = ws; ws += BG*256;
  int* flags   = (int*)ws;

  k_pre<<<48, 256, 0, stream>>>(deg_cnt, csp1, csp2, csp3, embf, ei, batch, flags);
  k_edge<<<cdiv(EE,256), 256, 0, stream>>>(ea, we, bedg, ei, flags, deg_cnt, csr_p);
  k_fix<<<cdiv(NELL,256), 256, 0, stream>>>(csr_p, deg_cnt);

  // layer 1: x(15) -> P1(32)
  k_layer<FIN,16,FH1,0><<<NN/16, 256, 0, stream>>>(x, nullptr,
      w1, b1, deg_cnt, csr_p, P1, csp1);
  k_stat<FH1><<<1, 64, 0, stream>>>(csp1, g1, be1, scs1);
  // layer 2: BN1(P1)(32) -> P2(64)
  k_layer<FH1,32,FH2,1><<<NN/8, 256, 0, stream>>>(P1, scs1,
      w2, b2, deg_cnt, csr_p, P2, csp2);
  k_stat<FH2><<<1, 64, 0, stream>>>(csp2, g2, be2, scs2);
  // layer 3: BN2(P2)(64) -> P3(64)
  k_layer<FH2,64,FH2,1><<<NN/4, 256, 0, stream>>>(P2, scs2,
      w3, b3, deg_cnt, csr_p, P3, csp3);
  k_stat<FH2><<<1, 64, 0, stream>>>(csp3, g3, be3, scs3);

  k_pool<<<256, 256, 0, stream>>>(P3, scs3, batch, flags, embf);
  k_fcA<<<128, 256, 0, stream>>>(embf, wf1, bf1, gf1, bef1, s1g, out);
  k_fcB<<<64, 256, 0, stream>>>(s1g, wf2, bf2, gf2, bef2, s2g);
  k_fc3<<<1, 256, 0, stream>>>(s2g, wf3, bf3, out);
}